// Round 3
// baseline (1385.739 us; speedup 1.0000x reference)
//
#include <hip/hip_runtime.h>
#include <hip/hip_bf16.h>

#define BB 32
#define SS 2048
#define DD 64
#define NTH 256
#define QT 16      // q rows per block
#define KTL 128    // k per tile
#define SCALE 0.125f   // 1/sqrt(64)

typedef __attribute__((ext_vector_type(4))) float f32x4;
typedef __attribute__((ext_vector_type(8))) short bf16x8;

union B8 { bf16x8 v; unsigned int u[4]; };

// pack 2 f32 -> packed bf16 pair (v_cvt_pk_bf16_f32 on gfx950)
__device__ __forceinline__ unsigned int pk2bf(float a, float b) {
    __hip_bfloat162 h = __float22bfloat162_rn(make_float2(a, b));
    unsigned int u;
    __builtin_memcpy(&u, &h, 4);
    return u;
}
__device__ __forceinline__ float bf_lo(unsigned int w) {
    return __builtin_bit_cast(float, w << 16);
}
__device__ __forceinline__ float bf_hi(unsigned int w) {
    return __builtin_bit_cast(float, w & 0xffff0000u);
}

// ---------------- pre-kernel A: K f32 -> bf16, layout preserved [b][k][d] ----------------
__global__ __launch_bounds__(NTH) void prepK(const float* __restrict__ K,
                                             unsigned short* __restrict__ Kbf) {
    const size_t i = (size_t)blockIdx.x * NTH + threadIdx.x;
    const float4* s = (const float4*)K;
    const float4 a = s[2 * i], c = s[2 * i + 1];
    uint4 w;
    w.x = pk2bf(a.x, a.y); w.y = pk2bf(a.z, a.w);
    w.z = pk2bf(c.x, c.y); w.w = pk2bf(c.z, c.w);
    ((uint4*)Kbf)[i] = w;
}

// ------- pre-kernel B: V [b][k][d] f32 -> VTh/VTl [b][d][k] bf16 (hi + residual-lo) -------
#define VPADF 68
__global__ __launch_bounds__(NTH) void prepV(const float* __restrict__ V,
                                             unsigned short* __restrict__ VTh,
                                             unsigned short* __restrict__ VTl) {
    __shared__ __align__(16) float lt[KTL * VPADF];            // 34816 B
    const int t  = threadIdx.x;
    const int b  = blockIdx.x >> 4;
    const int ck = blockIdx.x & 15;                            // 128-key chunk
    const float4* Vs = (const float4*)(V + ((size_t)b * SS + ck * KTL) * DD);
    #pragma unroll
    for (int i = 0; i < 8; ++i) {
        const int f4 = i * NTH + t;                            // coalesced
        float4 v = Vs[f4];
        const int kc = f4 >> 4, d4 = f4 & 15;
        *(float4*)&lt[kc * VPADF + d4 * 4] = v;
    }
    __syncthreads();
    const int d = t >> 2, kseg = t & 3;                        // d 0..63, 32 keys per kseg
    unsigned short* oh = VTh + ((size_t)b * DD + d) * SS + ck * KTL + kseg * 32;
    unsigned short* ol = VTl + ((size_t)b * DD + d) * SS + ck * KTL + kseg * 32;
    #pragma unroll
    for (int cch = 0; cch < 4; ++cch) {
        uint4 wh, wl;
        unsigned int* ph = (unsigned int*)&wh;
        unsigned int* pl = (unsigned int*)&wl;
        #pragma unroll
        for (int p = 0; p < 4; ++p) {
            const int k0 = kseg * 32 + cch * 8 + p * 2;
            const float a = lt[k0 * VPADF + d], c = lt[(k0 + 1) * VPADF + d];
            const unsigned int hw = pk2bf(a, c);
            ph[p] = hw;
            pl[p] = pk2bf(a - bf_lo(hw), c - bf_hi(hw));
        }
        *(uint4*)(oh + cch * 8) = wh;
        *(uint4*)(ol + cch * 8) = wl;
    }
}

// ------- pre-kernel C: bit-pack mask. Mp[b*SS+q][o] (o=wslot*16+li, o in [0,64)) has
// bit (2*tl+h) = M[b][q][tl*128 + (o>>4)*32 + h*16 + (o&15)].  Layout matches the main
// kernel's lane ownership exactly -> consumer needs 4 dword loads total, no shuffles.
// Per tl the wave's 2x64 dword reads cover 128 consecutive ints: fully coalesced. -------
__global__ __launch_bounds__(NTH) void packM(const int* __restrict__ M,
                                             unsigned int* __restrict__ Mp) {
    const int t = threadIdx.x, w = t >> 6, l = t & 63;
    const size_t row = (size_t)blockIdx.x * 4 + w;             // b*2048 + q
    const int* mr = M + row * SS;
    const int kb = (l >> 4) * 32 + (l & 15);
    unsigned int bits = 0;
    #pragma unroll
    for (int tl = 0; tl < 16; ++tl) {
        const int m0 = __builtin_nontemporal_load(&mr[tl * 128 + kb]);
        const int m1 = __builtin_nontemporal_load(&mr[tl * 128 + kb + 16]);
        bits |= (m0 ? 1u : 0u) << (2 * tl);
        bits |= (m1 ? 1u : 0u) << (2 * tl + 1);
    }
    Mp[row * 64 + l] = bits;
}

// ---------------- main kernel ----------------
// Block: (batch b, 16 q rows) x 2048 keys; 4 waves, wave owns keys w*32..+32 of each tile.
// K / V^T fragments read directly from global (L2-resident bf16). Mask: 4 dword loads of
// pre-packed bits per lane for the WHOLE kernel. No HBM-latency loads in either sweep.
// 8 blocks/CU (32 waves/CU). XCD-chunked bid swizzle: each XCD's L2 holds ~2 batches' ws.
__global__ __launch_bounds__(NTH, 8) void sdpa_mfma2(
    const float* __restrict__ Q, const unsigned int* __restrict__ Mp,
    const unsigned short* __restrict__ Kbf,
    const unsigned short* __restrict__ VTh, const unsigned short* __restrict__ VTl,
    float* __restrict__ ctx, float* __restrict__ attn)
{
    __shared__ __align__(16) unsigned char smem[17408];        // bnc 4 KB / scr 17 KB (overlaid)
    __shared__ float wsum[4][QT];
    __shared__ float inv_l[QT];
    unsigned short* bnc = (unsigned short*)smem;
    float*          scr = (float*)smem;

    const int t    = threadIdx.x;
    const int wave = t >> 6, l = t & 63, g = l >> 4, li = l & 15;
    const unsigned int bid = blockIdx.x;
    const unsigned int swz = (bid & 7) * 512 + (bid >> 3);     // 4096 % 8 == 0: bijective
    const int b    = swz >> 7;
    const int q0   = (swz & 127) * QT;

    const unsigned short* Kb  = Kbf + (size_t)b * SS * DD;
    const unsigned short* Vhb = VTh + (size_t)b * DD * SS;
    const unsigned short* Vlb = VTl + (size_t)b * DD * SS;
    float* attb = attn + ((size_t)b * SS + q0) * SS;

    // ---- mask bits: one dword per (q row) covers all 16 tiles x 2 halves for this lane ----
    unsigned int mreg[4];
    {
        const unsigned int* Mpb = Mp + ((size_t)b * SS + q0) * 64 + (wave * 16 + li);
        #pragma unroll
        for (int r = 0; r < 4; ++r) mreg[r] = Mpb[(size_t)(g * 4 + r) * 64];
    }

    // ---- Q fragments, split hi+lo bf16 (quasi-exact). m=li, k=g*8+j (+32h) ----
    B8 qh[2], ql[2];
    {
        const float* qp = Q + ((size_t)(b * SS + q0 + li)) * DD + g * 8;
        #pragma unroll
        for (int h = 0; h < 2; ++h) {
            float f[8];
            *(float4*)&f[0] = *(const float4*)(qp + h * 32);
            *(float4*)&f[4] = *(const float4*)(qp + h * 32 + 4);
            #pragma unroll
            for (int i = 0; i < 4; ++i) {
                unsigned int hw = pk2bf(f[2*i], f[2*i+1]);
                qh[h].u[i] = hw;
                ql[h].u[i] = pk2bf(f[2*i] - bf_lo(hw), f[2*i+1] - bf_hi(hw));
            }
        }
    }

    // per-lane K fragment base: row kc0 = wave*32+li, col byte for d = g*8
    const unsigned short* kf0 = Kb + (size_t)(wave * 32 + li) * DD + g * 8;

    auto qk = [&](int tl, f32x4& s0, f32x4& s1) {
        const unsigned short* p0 = kf0 + (size_t)tl * KTL * DD;
        #pragma unroll
        for (int h = 0; h < 2; ++h) {
            B8 k0, k1;
            k0.v = *(const bf16x8*)(p0 + 32 * h);              // row kc0, L2-hit
            k1.v = *(const bf16x8*)(p0 + 16 * DD + 32 * h);    // row kc0+16
            s0 = __builtin_amdgcn_mfma_f32_16x16x32_bf16(qh[h].v, k0.v, s0, 0, 0, 0);
            s0 = __builtin_amdgcn_mfma_f32_16x16x32_bf16(ql[h].v, k0.v, s0, 0, 0, 0);
            s1 = __builtin_amdgcn_mfma_f32_16x16x32_bf16(qh[h].v, k1.v, s1, 0, 0, 0);
            s1 = __builtin_amdgcn_mfma_f32_16x16x32_bf16(ql[h].v, k1.v, s1, 0, 0, 0);
        }
    };

    // ---- sweep 1: scores -> exp -> row sums. No global loads except L2 K-frags. ----
    float lsum[4] = {0.f, 0.f, 0.f, 0.f};

    #pragma unroll 1
    for (int tl = 0; tl < 16; ++tl) {
        f32x4 s0 = {0.f,0.f,0.f,0.f}, s1 = {0.f,0.f,0.f,0.f};
        qk(tl, s0, s1);
        #pragma unroll
        for (int r = 0; r < 4; ++r) {
            const float e0 = ((mreg[r] >> (2 * tl))     & 1u) ? 0.f : __expf(s0[r] * SCALE);
            const float e1 = ((mreg[r] >> (2 * tl + 1)) & 1u) ? 0.f : __expf(s1[r] * SCALE);
            lsum[r] += e0 + e1;
        }
    }

    // ---- row sums: reduce the 16 lanes per group, then cross-wave via LDS ----
    #pragma unroll
    for (int off = 8; off >= 1; off >>= 1)
        #pragma unroll
        for (int r = 0; r < 4; ++r)
            lsum[r] += __shfl_xor(lsum[r], off, 64);
    if (li == 0) {
        #pragma unroll
        for (int r = 0; r < 4; ++r) wsum[wave][g * 4 + r] = lsum[r];
    }
    __syncthreads();
    if (t < QT) inv_l[t] = 1.0f / (wsum[0][t] + wsum[1][t] + wsum[2][t] + wsum[3][t]);
    __syncthreads();
    float invl[4];
    #pragma unroll
    for (int r = 0; r < 4; ++r) invl[r] = inv_l[g * 4 + r];

    // ---- sweep 2: recompute scores, write normalized attn, P@V. No barriers. ----
    f32x4 cacc[4] = {{0.f,0.f,0.f,0.f},{0.f,0.f,0.f,0.f},{0.f,0.f,0.f,0.f},{0.f,0.f,0.f,0.f}};
    unsigned short* bw = bnc + wave * 512;                     // 1 KB per wave, wave-local

    #pragma unroll 1
    for (int tl = 0; tl < 16; ++tl) {
        f32x4 s0 = {0.f,0.f,0.f,0.f}, s1 = {0.f,0.f,0.f,0.f};
        qk(tl, s0, s1);
        const int kg0 = tl * KTL + wave * 32 + li;
        #pragma unroll
        for (int r = 0; r < 4; ++r) {
            const float e0 = ((mreg[r] >> (2 * tl))     & 1u) ? 0.f : __expf(s0[r] * SCALE);
            const float e1 = ((mreg[r] >> (2 * tl + 1)) & 1u) ? 0.f : __expf(s1[r] * SCALE);
            const size_t ao = (size_t)(g * 4 + r) * SS + kg0;
            attb[ao]      = e0 * invl[r];
            attb[ao + 16] = e1 * invl[r];
            // bounce (q^blk swizzle: 4-way max on b16 writes)
            const int q = g * 4 + r;
            const int b0 = li >> 3, b1 = (li + 16) >> 3;
            bw[((b0 * 16 + (q ^ b0)) << 3) + (li & 7)] = (unsigned short)pk2bf(e0, 0.f);
            bw[((b1 * 16 + (q ^ b1)) << 3) + (li & 7)] = (unsigned short)pk2bf(e1, 0.f);
        }
        // P A-frag: lane wants (q=li, k=g*8+j) -> block g*16 + (li^g), 16 B contiguous
        B8 pf;
        pf.v = *(const bf16x8*)(bw + ((g * 16 + (li ^ g)) << 3));
        const size_t vcol = (size_t)tl * KTL + wave * 32 + g * 8;
        #pragma unroll
        for (int c = 0; c < 4; ++c) {
            const size_t voff = (size_t)(c * 16 + li) * SS + vcol;
            B8 vh, vl;
            vh.v = *(const bf16x8*)(Vhb + voff);               // L2-hit
            vl.v = *(const bf16x8*)(Vlb + voff);
            cacc[c] = __builtin_amdgcn_mfma_f32_16x16x32_bf16(pf.v, vh.v, cacc[c], 0, 0, 0);
            cacc[c] = __builtin_amdgcn_mfma_f32_16x16x32_bf16(pf.v, vl.v, cacc[c], 0, 0, 0);
        }
    }

    // ---- ctx: cross-wave reduce via scratch (bnc dead), scale by 1/L ----
    __syncthreads();
    {
        const int row = wave * 64 + l;                         // 256 rows x stride 17 floats
        #pragma unroll
        for (int c = 0; c < 4; ++c)
            #pragma unroll
            for (int r = 0; r < 4; ++r)
                scr[row * 17 + c * 4 + r] = cacc[c][r];
    }
    __syncthreads();
    {
        const int q = t >> 4, d0 = (t & 15) * 4;
        float4 o;
        float* op = &o.x;
        #pragma unroll
        for (int dd = 0; dd < 4; ++dd) {
            const int d    = d0 + dd;
            const int lane = (q >> 2) * 16 + (d & 15);
            const int idx  = lane * 17 + (d >> 4) * 4 + (q & 3);
            float s = 0.f;
            #pragma unroll
            for (int w = 0; w < 4; ++w) s += scr[w * 64 * 17 + idx];
            op[dd] = s * inv_l[q];
        }
        *(float4*)(ctx + ((size_t)(b * SS + q0 + q)) * DD + d0) = o;
    }
}

extern "C" void kernel_launch(void* const* d_in, const int* in_sizes, int n_in,
                              void* d_out, int out_size, void* d_ws, size_t ws_size,
                              hipStream_t stream) {
    const float* Q = (const float*)d_in[0];
    const float* K = (const float*)d_in[1];
    const float* V = (const float*)d_in[2];
    const int*   M = (const int*)d_in[3];
    float* ctx  = (float*)d_out;                               // [32,2048,64]
    float* attn = (float*)d_out + (size_t)BB * SS * DD;        // [32,2048,2048]

    const size_t NE = (size_t)BB * SS * DD;                    // 4,194,304 elems
    unsigned short* Kbf = (unsigned short*)d_ws;               // 8 MB
    unsigned short* VTh = Kbf + NE;                            // 8 MB
    unsigned short* VTl = VTh + NE;                            // 8 MB
    unsigned int*   Mpk = (unsigned int*)(VTl + NE);           // 16.8 MB (total ~41 MB ws)

    prepK<<<dim3((unsigned)(NE / 8 / NTH)), dim3(NTH), 0, stream>>>(K, Kbf);
    prepV<<<dim3(BB * (SS / KTL)), dim3(NTH), 0, stream>>>(V, VTh, VTl);
    packM<<<dim3(BB * SS / 4), dim3(NTH), 0, stream>>>(M, Mpk);
    sdpa_mfma2<<<dim3(BB * (SS / QT)), dim3(NTH), 0, stream>>>(Q, Mpk, Kbf, VTh, VTl, ctx, attn);
}

// Round 5
// 1200.491 us; speedup vs baseline: 1.1543x; 1.1543x over previous
//
#include <hip/hip_runtime.h>
#include <hip/hip_bf16.h>

#define BB 32
#define SS 2048
#define DD 64
#define NTH 256
#define QT 32      // q rows per block (2 m-tiles of 16)
#define KTL 128    // k per tile
#define SCALE 0.125f   // 1/sqrt(64)

typedef __attribute__((ext_vector_type(4))) float f32x4;
typedef __attribute__((ext_vector_type(8))) short bf16x8;

union B8 { bf16x8 v; unsigned int u[4]; };

// pack 2 f32 -> packed bf16 pair (v_cvt_pk_bf16_f32 on gfx950)
__device__ __forceinline__ unsigned int pk2bf(float a, float b) {
    __hip_bfloat162 h = __float22bfloat162_rn(make_float2(a, b));
    unsigned int u;
    __builtin_memcpy(&u, &h, 4);
    return u;
}
__device__ __forceinline__ float bf_lo(unsigned int w) {
    return __builtin_bit_cast(float, w << 16);
}
__device__ __forceinline__ float bf_hi(unsigned int w) {
    return __builtin_bit_cast(float, w & 0xffff0000u);
}

// ---------------- pre-kernel A: K f32 -> bf16, layout preserved [b][k][d] ----------------
__global__ __launch_bounds__(NTH) void prepK(const float* __restrict__ K,
                                             unsigned short* __restrict__ Kbf) {
    const size_t i = (size_t)blockIdx.x * NTH + threadIdx.x;
    const float4* s = (const float4*)K;
    const float4 a = s[2 * i], c = s[2 * i + 1];
    uint4 w;
    w.x = pk2bf(a.x, a.y); w.y = pk2bf(a.z, a.w);
    w.z = pk2bf(c.x, c.y); w.w = pk2bf(c.z, c.w);
    ((uint4*)Kbf)[i] = w;
}

// ------- pre-kernel B: V [b][k][d] f32 -> VTh/VTl [b][d][k] bf16 (hi + residual-lo) -------
#define VPADF 68
__global__ __launch_bounds__(NTH) void prepV(const float* __restrict__ V,
                                             unsigned short* __restrict__ VTh,
                                             unsigned short* __restrict__ VTl) {
    __shared__ __align__(16) float lt[KTL * VPADF];            // 34816 B
    const int t  = threadIdx.x;
    const int b  = blockIdx.x >> 4;
    const int ck = blockIdx.x & 15;                            // 128-key chunk
    const float4* Vs = (const float4*)(V + ((size_t)b * SS + ck * KTL) * DD);
    #pragma unroll
    for (int i = 0; i < 8; ++i) {
        const int f4 = i * NTH + t;                            // coalesced
        float4 v = Vs[f4];
        const int kc = f4 >> 4, d4 = f4 & 15;
        *(float4*)&lt[kc * VPADF + d4 * 4] = v;
    }
    __syncthreads();
    const int d = t >> 2, kseg = t & 3;                        // d 0..63, 32 keys per kseg
    unsigned short* oh = VTh + ((size_t)b * DD + d) * SS + ck * KTL + kseg * 32;
    unsigned short* ol = VTl + ((size_t)b * DD + d) * SS + ck * KTL + kseg * 32;
    #pragma unroll
    for (int cch = 0; cch < 4; ++cch) {
        uint4 wh, wl;
        unsigned int* ph = (unsigned int*)&wh;
        unsigned int* pl = (unsigned int*)&wl;
        #pragma unroll
        for (int p = 0; p < 4; ++p) {
            const int k0 = kseg * 32 + cch * 8 + p * 2;
            const float a = lt[k0 * VPADF + d], c = lt[(k0 + 1) * VPADF + d];
            const unsigned int hw = pk2bf(a, c);
            ph[p] = hw;
            pl[p] = pk2bf(a - bf_lo(hw), c - bf_hi(hw));
        }
        *(uint4*)(oh + cch * 8) = wh;
        *(uint4*)(ol + cch * 8) = wl;
    }
}

// ------- pre-kernel C: bit-pack mask, even/odd key-pair layout.
// Word o = w*16 + li of row q: bit(2*tl)   = M[q][tl*128 + w*32 + 2*li]
//                              bit(2*tl+1) = M[q][tl*128 + w*32 + 2*li + 1] -------
__global__ __launch_bounds__(NTH) void packM(const int* __restrict__ M,
                                             unsigned int* __restrict__ Mp) {
    const int t = threadIdx.x, w = t >> 6, l = t & 63;
    const size_t row = (size_t)blockIdx.x * 4 + w;             // b*2048 + q
    const int* mr = M + row * SS;
    const int kb = (l >> 4) * 32 + 2 * (l & 15);
    unsigned int bits = 0;
    #pragma unroll
    for (int tl = 0; tl < 16; ++tl) {
        const int m0 = __builtin_nontemporal_load(&mr[tl * 128 + kb]);
        const int m1 = __builtin_nontemporal_load(&mr[tl * 128 + kb + 1]);
        bits |= (m0 ? 1u : 0u) << (2 * tl);
        bits |= (m1 ? 1u : 0u) << (2 * tl + 1);
    }
    Mp[row * 64 + l] = bits;
}

// ---------------- main kernel ----------------
// Block: (batch b, 32 q rows = 2 m-tiles) x 2048 keys; 4 waves, wave owns keys
// [w*32, w*32+32) of each 128-key tile. K/V fragments read once per tile per wave and
// reused for BOTH m-tiles (halves L2/L3 request traffic vs QT=16). Score accumulators
// hold key pairs (2li, 2li+1) -> attn stores are float2 = one full 128 B line per row
// per instruction (no partial-line write-allocate fills). Mask: 8 pre-packed dwords.
__global__ __launch_bounds__(NTH, 3) void sdpa_mfma3(
    const float* __restrict__ Q, const unsigned int* __restrict__ Mp,
    const unsigned short* __restrict__ Kbf,
    const unsigned short* __restrict__ VTh, const unsigned short* __restrict__ VTl,
    float* __restrict__ ctx, float* __restrict__ attn)
{
    __shared__ __align__(16) unsigned char smem[17408];        // bnc 8 KB / scr 17 KB (overlaid)
    __shared__ float wsum[4][QT];
    __shared__ float inv_l[QT];
    unsigned short* bnc = (unsigned short*)smem;
    float*          scr = (float*)smem;

    const int t    = threadIdx.x;
    const int wave = t >> 6, l = t & 63, g = l >> 4, li = l & 15;
    const unsigned int bid = blockIdx.x;
    const unsigned int swz = (bid & 7) * 256 + (bid >> 3);     // 2048 % 8 == 0: bijective
    const int b    = swz >> 6;
    const int q0   = (swz & 63) * QT;

    const unsigned short* Kb  = Kbf + (size_t)b * SS * DD;
    const unsigned short* Vhb = VTh + (size_t)b * DD * SS;
    const unsigned short* Vlb = VTl + (size_t)b * DD * SS;
    float* attb = attn + ((size_t)b * SS + q0) * SS;

    // ---- mask bits: one dword per q row (16 tiles x even/odd pair for this lane) ----
    unsigned int mreg[2][4];
    {
        const unsigned int* Mpb = Mp + ((size_t)b * SS + q0) * 64 + (wave * 16 + li);
        #pragma unroll
        for (int mt = 0; mt < 2; ++mt)
            #pragma unroll
            for (int r = 0; r < 4; ++r)
                mreg[mt][r] = Mpb[(size_t)(mt * 16 + g * 4 + r) * 64];
    }

    // ---- Q fragments, 2 m-tiles, split hi+lo bf16. A-frag: m=li, k=g*8+j (+32h) ----
    B8 qh[2][2], ql[2][2];
    #pragma unroll
    for (int mt = 0; mt < 2; ++mt) {
        const float* qp = Q + ((size_t)(b * SS + q0 + mt * 16 + li)) * DD + g * 8;
        #pragma unroll
        for (int h = 0; h < 2; ++h) {
            float f[8];
            *(float4*)&f[0] = *(const float4*)(qp + h * 32);
            *(float4*)&f[4] = *(const float4*)(qp + h * 32 + 4);
            #pragma unroll
            for (int i = 0; i < 4; ++i) {
                unsigned int hw = pk2bf(f[2*i], f[2*i+1]);
                qh[mt][h].u[i] = hw;
                ql[mt][h].u[i] = pk2bf(f[2*i] - bf_lo(hw), f[2*i+1] - bf_hi(hw));
            }
        }
    }

    // per-lane K fragment base: EVEN row wave*32 + 2*li (odd row = +DD shorts)
    const unsigned short* kfE = Kb + (size_t)(wave * 32 + 2 * li) * DD + g * 8;

    // QK^T for one tile, both m-tiles. sE: keys 2li (even), sO: keys 2li+1 (odd).
    auto qk = [&](int tl, f32x4 sE[2], f32x4 sO[2]) {
        const unsigned short* p0 = kfE + (size_t)tl * KTL * DD;
        #pragma unroll
        for (int h = 0; h < 2; ++h) {
            B8 kE, kO;
            kE.v = *(const bf16x8*)(p0 + 32 * h);              // even key row, L2/L3-hit
            kO.v = *(const bf16x8*)(p0 + DD + 32 * h);         // odd key row
            #pragma unroll
            for (int mt = 0; mt < 2; ++mt) {
                sE[mt] = __builtin_amdgcn_mfma_f32_16x16x32_bf16(qh[mt][h].v, kE.v, sE[mt], 0, 0, 0);
                sE[mt] = __builtin_amdgcn_mfma_f32_16x16x32_bf16(ql[mt][h].v, kE.v, sE[mt], 0, 0, 0);
                sO[mt] = __builtin_amdgcn_mfma_f32_16x16x32_bf16(qh[mt][h].v, kO.v, sO[mt], 0, 0, 0);
                sO[mt] = __builtin_amdgcn_mfma_f32_16x16x32_bf16(ql[mt][h].v, kO.v, sO[mt], 0, 0, 0);
            }
        }
    };

    // ---- sweep 1: scores -> exp -> row sums ----
    float lsum[2][4] = {{0.f,0.f,0.f,0.f},{0.f,0.f,0.f,0.f}};

    #pragma unroll 1
    for (int tl = 0; tl < 16; ++tl) {
        f32x4 sE[2] = {{0.f,0.f,0.f,0.f},{0.f,0.f,0.f,0.f}};
        f32x4 sO[2] = {{0.f,0.f,0.f,0.f},{0.f,0.f,0.f,0.f}};
        qk(tl, sE, sO);
        #pragma unroll
        for (int mt = 0; mt < 2; ++mt)
            #pragma unroll
            for (int r = 0; r < 4; ++r) {
                const float eE = ((mreg[mt][r] >> (2 * tl))     & 1u) ? 0.f : __expf(sE[mt][r] * SCALE);
                const float eO = ((mreg[mt][r] >> (2 * tl + 1)) & 1u) ? 0.f : __expf(sO[mt][r] * SCALE);
                lsum[mt][r] += eE + eO;
            }
    }

    // ---- row sums: reduce over the 16-lane group, then cross-wave via LDS ----
    #pragma unroll
    for (int off = 8; off >= 1; off >>= 1)
        #pragma unroll
        for (int mt = 0; mt < 2; ++mt)
            #pragma unroll
            for (int r = 0; r < 4; ++r)
                lsum[mt][r] += __shfl_xor(lsum[mt][r], off, 64);
    if (li == 0) {
        #pragma unroll
        for (int mt = 0; mt < 2; ++mt)
            #pragma unroll
            for (int r = 0; r < 4; ++r) wsum[wave][mt * 16 + g * 4 + r] = lsum[mt][r];
    }
    __syncthreads();
    if (t < QT) inv_l[t] = 1.0f / (wsum[0][t] + wsum[1][t] + wsum[2][t] + wsum[3][t]);
    __syncthreads();
    float invl[2][4];
    #pragma unroll
    for (int mt = 0; mt < 2; ++mt)
        #pragma unroll
        for (int r = 0; r < 4; ++r) invl[mt][r] = inv_l[mt * 16 + g * 4 + r];

    // ---- sweep 2: recompute scores, full-line attn stores, P@V (V frags shared by m-tiles) ----
    f32x4 cacc[2][4] = {{{0.f,0.f,0.f,0.f},{0.f,0.f,0.f,0.f},{0.f,0.f,0.f,0.f},{0.f,0.f,0.f,0.f}},
                        {{0.f,0.f,0.f,0.f},{0.f,0.f,0.f,0.f},{0.f,0.f,0.f,0.f},{0.f,0.f,0.f,0.f}}};
    unsigned short* bw = bnc + wave * 1024;                    // 2 KB per wave, wave-local

    #pragma unroll 1
    for (int tl = 0; tl < 16; ++tl) {
        f32x4 sE[2] = {{0.f,0.f,0.f,0.f},{0.f,0.f,0.f,0.f}};
        f32x4 sO[2] = {{0.f,0.f,0.f,0.f},{0.f,0.f,0.f,0.f}};
        qk(tl, sE, sO);
        const int kg0 = tl * KTL + wave * 32 + 2 * li;
        #pragma unroll
        for (int mt = 0; mt < 2; ++mt) {
            unsigned short* bwm = bw + mt * 512;
            #pragma unroll
            for (int r = 0; r < 4; ++r) {
                const float eE = ((mreg[mt][r] >> (2 * tl))     & 1u) ? 0.f : __expf(sE[mt][r] * SCALE);
                const float eO = ((mreg[mt][r] >> (2 * tl + 1)) & 1u) ? 0.f : __expf(sO[mt][r] * SCALE);
                // full 128 B line per (row, instruction): 16 lanes x float2
                const size_t ao = (size_t)(mt * 16 + g * 4 + r) * SS + kg0;
                *(float2*)&attb[ao] = make_float2(eE * invl[mt][r], eO * invl[mt][r]);
                // bounce: keys (2li, 2li+1) adjacent -> ONE u32 write; q^blk swizzle, 2-way max
                const int q = g * 4 + r;
                const int blk = li >> 2;
                *(unsigned int*)&bwm[((blk * 16 + (q ^ blk)) << 3) + 2 * (li & 3)] = pk2bf(eE, eO);
            }
        }
        // P A-frags: lane wants (q=li, k=g*8+j) -> block g, row li^g, 16 B contiguous
        B8 pf0, pf1;
        pf0.v = *(const bf16x8*)(bw + ((g * 16 + (li ^ g)) << 3));
        pf1.v = *(const bf16x8*)(bw + 512 + ((g * 16 + (li ^ g)) << 3));
        const size_t vcol = (size_t)tl * KTL + wave * 32 + g * 8;
        #pragma unroll
        for (int c = 0; c < 4; ++c) {
            const size_t voff = (size_t)(c * 16 + li) * SS + vcol;
            B8 vh, vl;
            vh.v = *(const bf16x8*)(Vhb + voff);               // shared by both m-tiles
            vl.v = *(const bf16x8*)(Vlb + voff);
            cacc[0][c] = __builtin_amdgcn_mfma_f32_16x16x32_bf16(pf0.v, vh.v, cacc[0][c], 0, 0, 0);
            cacc[0][c] = __builtin_amdgcn_mfma_f32_16x16x32_bf16(pf0.v, vl.v, cacc[0][c], 0, 0, 0);
            cacc[1][c] = __builtin_amdgcn_mfma_f32_16x16x32_bf16(pf1.v, vh.v, cacc[1][c], 0, 0, 0);
            cacc[1][c] = __builtin_amdgcn_mfma_f32_16x16x32_bf16(pf1.v, vl.v, cacc[1][c], 0, 0, 0);
        }
    }

    // ---- ctx: per m-tile, cross-wave reduce via scratch (bnc dead), scale by 1/L ----
    #pragma unroll 1
    for (int mt = 0; mt < 2; ++mt) {
        __syncthreads();
        {
            const int row = wave * 64 + l;                     // 256 rows x stride 17 floats
            #pragma unroll
            for (int c = 0; c < 4; ++c)
                #pragma unroll
                for (int r = 0; r < 4; ++r)
                    scr[row * 17 + c * 4 + r] = cacc[mt][c][r];
        }
        __syncthreads();
        {
            const int q = t >> 4, d0 = (t & 15) * 4;
            float4 o;
            float* op = &o.x;
            #pragma unroll
            for (int dd = 0; dd < 4; ++dd) {
                const int d    = d0 + dd;
                const int lane = (q >> 2) * 16 + (d & 15);
                const int idx  = lane * 17 + (d >> 4) * 4 + (q & 3);
                float s = 0.f;
                #pragma unroll
                for (int w = 0; w < 4; ++w) s += scr[w * 64 * 17 + idx];
                op[dd] = s * inv_l[mt * 16 + q];
            }
            *(float4*)(ctx + ((size_t)(b * SS + q0 + mt * 16 + q)) * DD + d0) = o;
        }
    }
}

extern "C" void kernel_launch(void* const* d_in, const int* in_sizes, int n_in,
                              void* d_out, int out_size, void* d_ws, size_t ws_size,
                              hipStream_t stream) {
    const float* Q = (const float*)d_in[0];
    const float* K = (const float*)d_in[1];
    const float* V = (const float*)d_in[2];
    const int*   M = (const int*)d_in[3];
    float* ctx  = (float*)d_out;                               // [32,2048,64]
    float* attn = (float*)d_out + (size_t)BB * SS * DD;        // [32,2048,2048]

    const size_t NE = (size_t)BB * SS * DD;                    // 4,194,304 elems
    unsigned short* Kbf = (unsigned short*)d_ws;               // 8 MB
    unsigned short* VTh = Kbf + NE;                            // 8 MB
    unsigned short* VTl = VTh + NE;                            // 8 MB
    unsigned int*   Mpk = (unsigned int*)(VTl + NE);           // 16.8 MB (total ~41 MB ws)

    prepK<<<dim3((unsigned)(NE / 8 / NTH)), dim3(NTH), 0, stream>>>(K, Kbf);
    prepV<<<dim3(BB * (SS / KTL)), dim3(NTH), 0, stream>>>(V, VTh, VTl);
    packM<<<dim3(BB * SS / 4), dim3(NTH), 0, stream>>>(M, Mpk);
    sdpa_mfma3<<<dim3(BB * (SS / QT)), dim3(NTH), 0, stream>>>(Q, Mpk, Kbf, VTh, VTl, ctx, attn);
}